// Round 15
// baseline (119.860 us; speedup 1.0000x reference)
//
#include <hip/hip_runtime.h>
#include <hip/hip_bf16.h>

typedef short bf16x8 __attribute__((ext_vector_type(8)));  // 8 bf16 (4 VGPRs)
typedef float f32x4 __attribute__((ext_vector_type(4)));

#define S_LEN 2048
#define NHEAD 16
#define DM 1024

#if __has_builtin(__builtin_amdgcn_exp2f)
#define EXP2(x) __builtin_amdgcn_exp2f(x)
#else
#define EXP2(x) exp2f(x)
#endif

__device__ __forceinline__ short f2bf(float f) {
  union { float f; unsigned u; } x; x.f = f;
  unsigned r = x.u + 0x7fffu + ((x.u >> 16) & 1u);  // RNE
  return (short)(r >> 16);
}

__device__ __forceinline__ unsigned cvt_pk_bf16(float lo, float hi) {
  unsigned r;
  asm("v_cvt_pk_bf16_f32 %0, %1, %2" : "=v"(r) : "v"(lo), "v"(hi));
  return r;
}

__device__ __forceinline__ void pl32swap(unsigned& a, unsigned& b) {
#if __has_builtin(__builtin_amdgcn_permlane32_swap)
  auto r = __builtin_amdgcn_permlane32_swap(a, b, false, false);
  a = r[0]; b = r[1];
#else
  asm volatile("v_permlane32_swap_b32 %0, %1" : "+v"(a), "+v"(b));
#endif
}
__device__ __forceinline__ void pl16swap(unsigned& a, unsigned& b) {
#if __has_builtin(__builtin_amdgcn_permlane16_swap)
  auto r = __builtin_amdgcn_permlane16_swap(a, b, false, false);
  a = r[0]; b = r[1];
#else
  asm volatile("v_permlane16_swap_b32 %0, %1" : "+v"(a), "+v"(b));
#endif
}

__device__ __forceinline__ void gload16(const void* g, void* l) {
  __builtin_amdgcn_global_load_lds(
      (const __attribute__((address_space(1))) void*)g,
      (__attribute__((address_space(3))) void*)l, 16, 0, 0);
}

// ---------------- prep: fused xcvt (planes 0-2) + weight transpose (plane 3)
// + mask->bf16 table. grid (1024, 4), 256 threads.
__global__ __launch_bounds__(256) void prep(const float* __restrict__ query, const float* __restrict__ key,
                                            const float* __restrict__ value,
                                            const float* __restrict__ Wq, const float* __restrict__ Wk,
                                            const float* __restrict__ Wv, const float* __restrict__ Wo,
                                            const int* __restrict__ mask,
                                            short* xq, short* xk, short* xv,
                                            short* Tq, short* Tk, short* Tv, short* To, short* Mb) {
  const int z = blockIdx.y;
  const int tid = threadIdx.x;
  if (z < 3) {
    const float* src = (z == 0) ? query : (z == 1) ? key : value;
    short* dst = (z == 0) ? xq : (z == 1) ? xk : xv;
    const size_t base = ((size_t)blockIdx.x * 256 + tid) * 16;
    float4 a = *(const float4*)&src[base];
    float4 b = *(const float4*)&src[base + 4];
    float4 c = *(const float4*)&src[base + 8];
    float4 d = *(const float4*)&src[base + 12];
    bf16x8 o0, o1;
    o0[0] = f2bf(a.x); o0[1] = f2bf(a.y); o0[2] = f2bf(a.z); o0[3] = f2bf(a.w);
    o0[4] = f2bf(b.x); o0[5] = f2bf(b.y); o0[6] = f2bf(b.z); o0[7] = f2bf(b.w);
    o1[0] = f2bf(c.x); o1[1] = f2bf(c.y); o1[2] = f2bf(c.z); o1[3] = f2bf(c.w);
    o1[4] = f2bf(d.x); o1[5] = f2bf(d.y); o1[6] = f2bf(d.z); o1[7] = f2bf(d.w);
    *(bf16x8*)&dst[base] = o0;
    *(bf16x8*)&dst[base + 8] = o1;
    return;
  }
  // plane 3: 1024 blocks = 4 weights x 256 tiles of 64x64
  const int wsel = blockIdx.x >> 8;
  const int within = blockIdx.x & 255;
  const float* W = (wsel == 0) ? Wq : (wsel == 1) ? Wk : (wsel == 2) ? Wv : Wo;
  short* T = (wsel == 0) ? Tq : (wsel == 1) ? Tk : (wsel == 2) ? Tv : To;
  const int k0 = ((within >> 4) & 15) * 64, n0 = (within & 15) * 64;
  __shared__ short Tl[64][72];
  const int r = tid >> 2, c0 = (tid & 3) * 16;
#pragma unroll
  for (int j = 0; j < 4; j++) {
    float4 v = *(const float4*)&W[(size_t)(k0 + r) * DM + n0 + c0 + 4 * j];
    Tl[r][c0 + 4 * j + 0] = f2bf(v.x);
    Tl[r][c0 + 4 * j + 1] = f2bf(v.y);
    Tl[r][c0 + 4 * j + 2] = f2bf(v.z);
    Tl[r][c0 + 4 * j + 3] = f2bf(v.w);
  }
  if (blockIdx.x < 16) {  // mask table: 16 x 256 = 4096 entries
    int i = blockIdx.x * 256 + tid;
    Mb[i] = mask[i] ? (short)0x3F80 : (short)0;
  }
  __syncthreads();
  bf16x8 o0, o1;
#pragma unroll
  for (int j = 0; j < 8; j++) { o0[j] = Tl[c0 + j][r]; o1[j] = Tl[c0 + 8 + j][r]; }
  *(bf16x8*)&T[(size_t)(n0 + r) * DM + k0 + c0] = o0;
  *(bf16x8*)&T[(size_t)(n0 + r) * DM + k0 + c0 + 8] = o1;
}

// ---------------- gemm5: m97-style 128x128 tile, single-buffer LDS (32 KB),
// 2-barrier K-step, 4 waves (2x2, 64x64 each), XCD-chunked.
// MODE 0: fused QKV projection — A = [12288][1024] bf16 (xq|xk|xv), Bt
//   row-block picked by which=by>>5; epilogue 0->Qb(scaled), 1->Kb,
//   2->VbT (transposed, mask-zeroed). grid (8, 96).
// MODE 1: plain C = A @ Bt^T, f32 row-major out (final O @ Wo). grid (8, 32).
template<int MODE>
__global__ __launch_bounds__(256) void gemm5(const short* __restrict__ A, const short* __restrict__ Wt,
                                             const int* __restrict__ mask,
                                             short* __restrict__ Qb, short* __restrict__ Kb,
                                             short* __restrict__ VbT, float* __restrict__ Out) {
  __shared__ __align__(16) short Al[128 * 64];
  __shared__ __align__(16) short Bl[128 * 64];
  const int tid = threadIdx.x;
  const int lane = tid & 63, w = tid >> 6;
  const int wm = w >> 1, wn = w & 1;
  const int lr = lane & 15, g = lane >> 4;

  const int flat = blockIdx.y * gridDim.x + blockIdx.x;
  const int chunk = (gridDim.x * gridDim.y) >> 3;
  const int wid = (flat & 7) * chunk + (flat >> 3);
  const int bx = wid & 7, by = wid >> 3;
  const int n0 = bx * 128, m0 = by * 128;
  const int which = (MODE == 0) ? (by >> 5) : 0;

  f32x4 acc[4][4];
#pragma unroll
  for (int i = 0; i < 4; i++)
#pragma unroll
    for (int j = 0; j < 4; j++) acc[i][j] = (f32x4){0.f, 0.f, 0.f, 0.f};

  const int srow = lane >> 3;
  const int sch = (lane & 7) ^ (srow & 7);
  const short* gA = A + (size_t)(m0 + w * 32 + srow) * 1024 + 8 * sch;
  const short* gB = Wt + (size_t)(which * 1024 + n0 + w * 32 + srow) * 1024 + 8 * sch;

#define STAGE(kk)                                                                   \
  do {                                                                              \
    _Pragma("unroll") for (int c = 0; c < 4; c++)                                   \
        gload16(gA + (size_t)c * 8 * 1024 + (kk), &Al[(w * 32 + c * 8) * 64]);      \
    _Pragma("unroll") for (int c = 0; c < 4; c++)                                   \
        gload16(gB + (size_t)c * 8 * 1024 + (kk), &Bl[(w * 32 + c * 8) * 64]);      \
  } while (0)

  const int nsteps = 16;  // K=1024 / 64
  STAGE(0);
  for (int t = 0; t < nsteps; t++) {
    __syncthreads();  // staged loads visible (vmcnt drained before barrier)
#pragma unroll
    for (int kc = 0; kc < 2; kc++) {
      bf16x8 af[4], bfr[4];
#pragma unroll
      for (int mt = 0; mt < 4; mt++) {
        int row = wm * 64 + mt * 16 + lr;
        af[mt] = *(const bf16x8*)&Al[row * 64 + 8 * ((kc * 4 + g) ^ (lr & 7))];
      }
#pragma unroll
      for (int nt = 0; nt < 4; nt++) {
        int row = wn * 64 + nt * 16 + lr;
        bfr[nt] = *(const bf16x8*)&Bl[row * 64 + 8 * ((kc * 4 + g) ^ (lr & 7))];
      }
      __builtin_amdgcn_s_setprio(1);
#pragma unroll
      for (int mt = 0; mt < 4; mt++)
#pragma unroll
        for (int nt = 0; nt < 4; nt++)
          acc[mt][nt] = __builtin_amdgcn_mfma_f32_16x16x32_bf16(af[mt], bfr[nt], acc[mt][nt], 0, 0, 0);
      __builtin_amdgcn_s_setprio(0);
    }
    __syncthreads();  // all LDS reads done before overwrite
    if (t + 1 < nsteps) STAGE((t + 1) << 6);
  }
#undef STAGE

#pragma unroll
  for (int mt = 0; mt < 4; mt++)
#pragma unroll
    for (int nt = 0; nt < 4; nt++) {
      const int col = n0 + wn * 64 + nt * 16 + lr;
      if (MODE == 1) {
#pragma unroll
        for (int r = 0; r < 4; r++) {
          int row = m0 + wm * 64 + mt * 16 + g * 4 + r;
          Out[(size_t)row * DM + col] = acc[mt][nt][r];
        }
      } else {
        const int h = col >> 6, d = col & 63;
        if (which == 2) {
          const int tok = (m0 & 4095) + wm * 64 + mt * 16 + g * 4;  // 4 consecutive s
          const int bb = tok >> 11, s = tok & (S_LEN - 1);
          int4 mv = *(const int4*)&mask[bb * S_LEN + s];
          union { short s4[4]; uint2 u; } pk;
          pk.s4[0] = mv.x ? f2bf(acc[mt][nt][0]) : (short)0;
          pk.s4[1] = mv.y ? f2bf(acc[mt][nt][1]) : (short)0;
          pk.s4[2] = mv.z ? f2bf(acc[mt][nt][2]) : (short)0;
          pk.s4[3] = mv.w ? f2bf(acc[mt][nt][3]) : (short)0;
          *(uint2*)&VbT[(((size_t)(bb * NHEAD + h)) * 64 + d) * S_LEN + s] = pk.u;
        } else {
          short* dst = (which == 0) ? Qb : Kb;
          const float scale = (which == 0) ? 0.18033688011f : 1.f;
#pragma unroll
          for (int r = 0; r < 4; r++) {
            int tok = (m0 & 4095) + wm * 64 + mt * 16 + g * 4 + r;
            int bb = tok >> 11, s = tok & (S_LEN - 1);
            dst[(((size_t)(bb * NHEAD + h)) * S_LEN + s) * 64 + d] = f2bf(acc[mt][nt][r] * scale);
          }
        }
      }
    }
}

// ---------------- gemm2 (fallback small-ws path, unchanged)
template<int AM, int BMODE, int CM>
__global__ __launch_bounds__(256) void gemm2(const void* __restrict__ Ap, const void* __restrict__ Bp,
                                             void* __restrict__ Cp, int M, int N, int K) {
  __shared__ __align__(16) short Al[128][72];
  __shared__ __align__(16) short Bl[64][72];
  const int tid = threadIdx.x;
  const int lane = tid & 63, w = tid >> 6;
  const int wm = w >> 1, wn = w & 1;
  const int lr = lane & 15, g = lane >> 4;
  const int m0 = blockIdx.y * 128, n0 = blockIdx.x * 64;

  f32x4 acc[4][2];
#pragma unroll
  for (int i = 0; i < 4; i++)
#pragma unroll
    for (int j = 0; j < 2; j++) acc[i][j] = (f32x4){0.f, 0.f, 0.f, 0.f};

  const int ar = tid >> 1, ac = (tid & 1) * 32;
  const int br = tid >> 2, bc = (tid & 3) * 16;

  float4 la[8]; bf16x8 la8[4];
  float4 lb[4]; bf16x8 lb8[2];

#define LOADA(kk)                                                                        \
  do {                                                                                   \
    if (AM == 0) {                                                                       \
      const float* A = (const float*)Ap;                                                 \
      _Pragma("unroll") for (int j = 0; j < 8; j++)                                      \
          la[j] = *(const float4*)&A[(size_t)(m0 + ar) * K + (kk) + ac + 4 * j];         \
    } else {                                                                             \
      const short* A = (const short*)Ap;                                                 \
      _Pragma("unroll") for (int j = 0; j < 4; j++)                                      \
          la8[j] = *(const bf16x8*)&A[(size_t)(m0 + ar) * K + (kk) + ac + 8 * j];        \
    }                                                                                    \
  } while (0)

#define LOADB(kk)                                                                        \
  do {                                                                                   \
    if (BMODE == 0) {                                                                    \
      const float* B = (const float*)Bp;                                                 \
      _Pragma("unroll") for (int j = 0; j < 4; j++)                                      \
          lb[j] = *(const float4*)&B[(size_t)(n0 + br) * K + (kk) + bc + 4 * j];         \
    } else if (BMODE == 1) {                                                             \
      const short* B = (const short*)Bp;                                                 \
      _Pragma("unroll") for (int j = 0; j < 2; j++)                                      \
          lb8[j] = *(const bf16x8*)&B[(size_t)(n0 + br) * K + (kk) + bc + 8 * j];        \
    } else {                                                                             \
      const float* B = (const float*)Bp;                                                 \
      _Pragma("unroll") for (int j = 0; j < 4; j++)                                      \
          lb[j] = *(const float4*)&B[(size_t)((kk) + br) * N + n0 + bc + 4 * j];         \
    }                                                                                    \
  } while (0)

  const int nsteps = K >> 6;
  LOADA(0); LOADB(0);

  for (int t = 0; t < nsteps; t++) {
    __syncthreads();
    if (AM == 0) {
#pragma unroll
      for (int j = 0; j < 4; j++) {
        float4 v0 = la[2 * j], v1 = la[2 * j + 1];
        bf16x8 tt;
        tt[0] = f2bf(v0.x); tt[1] = f2bf(v0.y); tt[2] = f2bf(v0.z); tt[3] = f2bf(v0.w);
        tt[4] = f2bf(v1.x); tt[5] = f2bf(v1.y); tt[6] = f2bf(v1.z); tt[7] = f2bf(v1.w);
        *(bf16x8*)&Al[ar][ac + 8 * j] = tt;
      }
    } else {
#pragma unroll
      for (int j = 0; j < 4; j++) *(bf16x8*)&Al[ar][ac + 8 * j] = la8[j];
    }
    if (BMODE == 0) {
#pragma unroll
      for (int j = 0; j < 2; j++) {
        float4 v0 = lb[2 * j], v1 = lb[2 * j + 1];
        bf16x8 tt;
        tt[0] = f2bf(v0.x); tt[1] = f2bf(v0.y); tt[2] = f2bf(v0.z); tt[3] = f2bf(v0.w);
        tt[4] = f2bf(v1.x); tt[5] = f2bf(v1.y); tt[6] = f2bf(v1.z); tt[7] = f2bf(v1.w);
        *(bf16x8*)&Bl[br][bc + 8 * j] = tt;
      }
    } else if (BMODE == 1) {
#pragma unroll
      for (int j = 0; j < 2; j++) *(bf16x8*)&Bl[br][bc + 8 * j] = lb8[j];
    } else {
#pragma unroll
      for (int j = 0; j < 4; j++) {
        float4 v = lb[j];
        Bl[bc + 4 * j + 0][br] = f2bf(v.x);
        Bl[bc + 4 * j + 1][br] = f2bf(v.y);
        Bl[bc + 4 * j + 2][br] = f2bf(v.z);
        Bl[bc + 4 * j + 3][br] = f2bf(v.w);
      }
    }
    __syncthreads();
    if (t + 1 < nsteps) { LOADA((t + 1) << 6); LOADB((t + 1) << 6); }
#pragma unroll
    for (int kc = 0; kc < 2; kc++) {
      bf16x8 af[4], bfr[2];
#pragma unroll
      for (int mt = 0; mt < 4; mt++) af[mt] = *(const bf16x8*)&Al[wm * 64 + mt * 16 + lr][kc * 32 + g * 8];
#pragma unroll
      for (int nt = 0; nt < 2; nt++) bfr[nt] = *(const bf16x8*)&Bl[wn * 32 + nt * 16 + lr][kc * 32 + g * 8];
#pragma unroll
      for (int mt = 0; mt < 4; mt++)
#pragma unroll
        for (int nt = 0; nt < 2; nt++)
          acc[mt][nt] = __builtin_amdgcn_mfma_f32_16x16x32_bf16(af[mt], bfr[nt], acc[mt][nt], 0, 0, 0);
    }
  }
#undef LOADA
#undef LOADB

#pragma unroll
  for (int mt = 0; mt < 4; mt++)
#pragma unroll
    for (int nt = 0; nt < 2; nt++)
#pragma unroll
      for (int r = 0; r < 4; r++) {
        int row = m0 + wm * 64 + mt * 16 + g * 4 + r;
        int col = n0 + wn * 32 + nt * 16 + lr;
        if (CM == 0) {
          ((float*)Cp)[(size_t)row * N + col] = acc[mt][nt][r];
        } else if (CM == 1 || CM == 3) {
          float v = (CM == 3) ? acc[mt][nt][r] * 0.18033688011f : acc[mt][nt][r];
          int b = row >> 11, s = row & (S_LEN - 1);
          int h = col >> 6, d = col & 63;
          ((short*)Cp)[(((size_t)(b * NHEAD + h)) * S_LEN + s) * 64 + d] = f2bf(v);
        } else {
          int h = row >> 6, d = row & 63;
          int b = col >> 11, s = col & (S_LEN - 1);
          ((short*)Cp)[(((size_t)(b * NHEAD + h)) * 64 + d) * S_LEN + s] = f2bf(acc[mt][nt][r]);
        }
      }
}

// ---------------- attn11 (round-13 proven): 2q x 2k wave split, dbuf,
// mask-free inner loop, permlane P redistribution, LDS merge of k-halves.
__global__ __launch_bounds__(256, 3) void attn11(const short* __restrict__ Qb,
                                                 const short* __restrict__ Kb,
                                                 const short* __restrict__ VbT,
                                                 const short* __restrict__ Mb,
                                                 short* __restrict__ Ob) {
  __shared__ __align__(16) short Kl[2][64][64];
  __shared__ __align__(16) short Vl[2][64][64];
  __shared__ __align__(16) short Ml[S_LEN];

  const int tid = threadIdx.x;
  const int lane = tid & 63, w = tid >> 6;
  const int lr = lane & 15, g = lane >> 4;
  const int wq = w >> 1, wk = w & 1;

  const int flat = blockIdx.y * gridDim.x + blockIdx.x;
  const int wid = (flat & 7) * 128 + (flat >> 3);
  const int qblk = wid & 31, bh = wid >> 5;
  const int b = bh >> 4, h = bh & 15;
  const int qbase = qblk * 64;
  const size_t hoff = (size_t)bh * S_LEN * 64;

  *(bf16x8*)&Ml[tid * 8] = *(const bf16x8*)&Mb[b * S_LEN + tid * 8];

  bf16x8 qf[2][2];
#pragma unroll
  for (int qfr = 0; qfr < 2; qfr++)
#pragma unroll
    for (int kh = 0; kh < 2; kh++)
      qf[qfr][kh] = *(const bf16x8*)&Qb[hoff + (size_t)(qbase + wq * 32 + qfr * 16 + lr) * 64 + kh * 32 + g * 8];

  f32x4 o_acc[2][4];
  f32x4 o_l[2];
#pragma unroll
  for (int qfr = 0; qfr < 2; qfr++) {
    o_l[qfr] = (f32x4){0.f, 0.f, 0.f, 0.f};
#pragma unroll
    for (int dg = 0; dg < 4; dg++) o_acc[qfr][dg] = (f32x4){0.f, 0.f, 0.f, 0.f};
  }

  const int srow = lane >> 3;
  const int sch = (lane & 7) ^ (srow & 7);
  const short* gK = Kb + hoff + (size_t)(w * 16 + srow) * 64 + 8 * sch;
  const short* gV = VbT + hoff + (size_t)(w * 16 + srow) * S_LEN + 8 * sch;

#define STAGEKV(buf, kb)                                                         \
  do {                                                                           \
    _Pragma("unroll") for (int c = 0; c < 2; c++)                                \
        gload16(gK + (size_t)((kb) + c * 8) * 64, &Kl[buf][w * 16 + c * 8][0]);  \
    _Pragma("unroll") for (int c = 0; c < 2; c++)                                \
        gload16(gV + (size_t)c * 8 * S_LEN + (kb), &Vl[buf][w * 16 + c * 8][0]); \
  } while (0)

  const int NT = S_LEN / 64;
  STAGEKV(0, 0);
  int buf = 0;

  for (int t = 0; t < NT; t++) {
    const int kb = t * 64;
    __syncthreads();
    if (t + 1 < NT) STAGEKV(buf ^ 1, kb + 64);

    bf16x8 mf = *(const bf16x8*)&Ml[kb + wk * 32 + g * 8];

    bf16x8 kfr[2][2];
#pragma unroll
    for (int nt = 0; nt < 2; nt++)
#pragma unroll
      for (int kh = 0; kh < 2; kh++)
        kfr[nt][kh] = *(const bf16x8*)&Kl[buf][wk * 32 + nt * 16 + lr][8 * ((4 * kh + g) ^ (lr & 7))];

    bf16x8 vfr[4];
#pragma unroll
    for (int dg = 0; dg < 4; dg++)
      vfr[dg] = *(const bf16x8*)&Vl[buf][dg * 16 + lr][8 * ((4 * wk + g) ^ (lr & 7))];

#pragma unroll
    for (int qfr = 0; qfr < 2; qfr++) {
      f32x4 s[2];
#pragma unroll
      for (int nt = 0; nt < 2; nt++) s[nt] = (f32x4){0.f, 0.f, 0.f, 0.f};
      __builtin_amdgcn_s_setprio(1);
#pragma unroll
      for (int nt = 0; nt < 2; nt++) {
        s[nt] = __builtin_amdgcn_mfma_f32_16x16x32_bf16(kfr[nt][0], qf[qfr][0], s[nt], 0, 0, 0);
        s[nt] = __builtin_amdgcn_mfma_f32_16x16x32_bf16(kfr[nt][1], qf[qfr][1], s[nt], 0, 0, 0);
      }
      __builtin_amdgcn_s_setprio(0);

      unsigned W0[2], W1[2];
#pragma unroll
      for (int nt = 0; nt < 2; nt++) {
        float p0 = EXP2(s[nt][0]);
        float p1 = EXP2(s[nt][1]);
        float p2 = EXP2(s[nt][2]);
        float p3 = EXP2(s[nt][3]);
        W0[nt] = cvt_pk_bf16(p0, p1);
        W1[nt] = cvt_pk_bf16(p2, p3);
      }

      bf16x8 pf;
      {
        unsigned a0 = W0[0], b0 = W0[1];
        unsigned a1 = W1[0], b1 = W1[1];
        pl32swap(a0, b0); pl16swap(a0, b0);
        pl32swap(a1, b1); pl16swap(a1, b1);
        union { unsigned u[4]; bf16x8 v; } pk;
        pk.u[0] = a0; pk.u[1] = a1; pk.u[2] = b0; pk.u[3] = b1;
        pf = pk.v;
      }

      __builtin_amdgcn_s_setprio(1);
#pragma unroll
      for (int dg = 0; dg < 4; dg++)
        o_acc[qfr][dg] = __builtin_amdgcn_mfma_f32_16x16x32_bf16(pf, vfr[dg], o_acc[qfr][dg], 0, 0, 0);
      o_l[qfr] = __builtin_amdgcn_mfma_f32_16x16x32_bf16(pf, mf, o_l[qfr], 0, 0, 0);
      __builtin_amdgcn_s_setprio(0);
    }
    buf ^= 1;
  }
#undef STAGEKV

  __syncthreads();
  float* Sf = (float*)&Kl[0][0][0];
  float* Sl = (float*)&Vl[0][0][0];
  if (wk == 1) {
#pragma unroll
    for (int qfr = 0; qfr < 2; qfr++) {
#pragma unroll
      for (int dg = 0; dg < 4; dg++)
#pragma unroll
        for (int r = 0; r < 4; r++)
          Sf[(wq * 32 + qfr * 16 + 4 * g + r) * 64 + dg * 16 + lr] = o_acc[qfr][dg][r];
      if (lr == 0)
#pragma unroll
        for (int r = 0; r < 4; r++)
          Sl[wq * 32 + qfr * 16 + 4 * g + r] = o_l[qfr][r];
    }
  }
  __syncthreads();
  if (wk == 0) {
#pragma unroll
    for (int qfr = 0; qfr < 2; qfr++)
#pragma unroll
      for (int r = 0; r < 4; r++) {
        int ql = wq * 32 + qfr * 16 + 4 * g + r;
        float l = o_l[qfr][r] + Sl[ql];
        float inv = 1.f / l;
        int qr = qbase + ql;
#pragma unroll
        for (int dg = 0; dg < 4; dg++) {
          float ov = o_acc[qfr][dg][r] + Sf[ql * 64 + dg * 16 + lr];
          Ob[((size_t)b * S_LEN + qr) * DM + h * 64 + dg * 16 + lr] = f2bf(ov * inv);
        }
      }
  }
}

// ---------------- attn7 (small-ws fallback, self-masking, unchanged)
__global__ __launch_bounds__(256, 4) void attn7(const short* __restrict__ Qb,
                                                const short* __restrict__ Kb,
                                                const short* __restrict__ VbT,
                                                const int* __restrict__ mask,
                                                short* __restrict__ Ob) {
  __shared__ __align__(16) short Kl[2][64][64];
  __shared__ __align__(16) short Vl[2][64][64];

  const int tid = threadIdx.x;
  const int lane = tid & 63, w = tid >> 6;
  const int lr = lane & 15, g = lane >> 4;

  const int flat = blockIdx.y * gridDim.x + blockIdx.x;
  const int wid = (flat & 7) * 128 + (flat >> 3);
  const int qblk = wid & 31, bh = wid >> 5;
  const int b = bh >> 4, h = bh & 15;
  const int qbase = qblk * 64;
  const size_t hoff = (size_t)bh * S_LEN * 64;

  bf16x8 qf[2];
#pragma unroll
  for (int kh = 0; kh < 2; kh++)
    qf[kh] = *(const bf16x8*)&Qb[hoff + (size_t)(qbase + w * 16 + lr) * 64 + kh * 32 + g * 8];

  f32x4 o_acc[4];
  float lsum = 0.f;
#pragma unroll
  for (int dg = 0; dg < 4; dg++) o_acc[dg] = (f32x4){0.f, 0.f, 0.f, 0.f};

  const int* maskb = mask + b * S_LEN;
  const int srow = lane >> 3;
  const int sch = (lane & 7) ^ (srow & 7);
  const short* gK = Kb + hoff + (size_t)(w * 16 + srow) * 64 + 8 * sch;
  const short* gV = VbT + hoff + (size_t)(w * 16 + srow) * S_LEN + 8 * sch;

#define STAGEKV(buf, kb)                                                         \
  do {                                                                           \
    _Pragma("unroll") for (int c = 0; c < 2; c++)                                \
        gload16(gK + (size_t)(kb + c * 8) * 64, &Kl[buf][w * 16 + c * 8][0]);    \
    _Pragma("unroll") for (int c = 0; c < 2; c++)                                \
        gload16(gV + (size_t)c * 8 * S_LEN + (kb), &Vl[buf][w * 16 + c * 8][0]); \
  } while (0)

  const int NT = S_LEN / 64;
  STAGEKV(0, 0);
  int buf = 0;

  for (int t = 0; t < NT; t++) {
    const int kb = t * 64;
    __syncthreads();
    if (t + 1 < NT) STAGEKV(buf ^ 1, kb + 64);

    float bias[4][4];
#pragma unroll
    for (int nt = 0; nt < 4; nt++) {
      int4 mv = *(const int4*)&maskb[kb + nt * 16 + 4 * g];
      bias[nt][0] = mv.x ? 0.f : -1e30f;
      bias[nt][1] = mv.y ? 0.f : -1e30f;
      bias[nt][2] = mv.z ? 0.f : -1e30f;
      bias[nt][3] = mv.w ? 0.f : -1e30f;
    }

    f32x4 s[4];
#pragma unroll
    for (int nt = 0; nt < 4; nt++) s[nt] = (f32x4){0.f, 0.f, 0.f, 0.f};
    __builtin_amdgcn_s_setprio(1);
#pragma unroll
    for (int nt = 0; nt < 4; nt++) {
      bf16x8 k0 = *(const bf16x8*)&Kl[buf][nt * 16 + lr][8 * (g ^ (lr & 7))];
      bf16x8 k1 = *(const bf16x8*)&Kl[buf][nt * 16 + lr][8 * ((4 + g) ^ (lr & 7))];
      s[nt] = __builtin_amdgcn_mfma_f32_16x16x32_bf16(k0, qf[0], s[nt], 0, 0, 0);
      s[nt] = __builtin_amdgcn_mfma_f32_16x16x32_bf16(k1, qf[1], s[nt], 0, 0, 0);
    }
    __builtin_amdgcn_s_setprio(0);

    unsigned W0[4], W1[4];
#pragma unroll
    for (int nt = 0; nt < 4; nt++) {
      float p0 = EXP2(s[nt][0] + bias[nt][0]);
      float p1 = EXP2(s[nt][1] + bias[nt][1]);
      float p2 = EXP2(s[nt][2] + bias[nt][2]);
      float p3 = EXP2(s[nt][3] + bias[nt][3]);
      lsum += (p0 + p1) + (p2 + p3);
      W0[nt] = cvt_pk_bf16(p0, p1);
      W1[nt] = cvt_pk_bf16(p2, p3);
    }

    bf16x8 pf[2];
#pragma unroll
    for (int kh = 0; kh < 2; kh++) {
      unsigned a0 = W0[2 * kh], b0 = W0[2 * kh + 1];
      unsigned a1 = W1[2 * kh], b1 = W1[2 * kh + 1];
      pl32swap(a0, b0); pl16swap(a0, b0);
      pl32swap(a1, b1); pl16swap(a1, b1);
      union { unsigned u[4]; bf16x8 v; } pk;
      pk.u[0] = a0; pk.u[1] = a1; pk.u[2] = b0; pk.u[3] = b1;
      pf[kh] = pk.v;
    }

    __builtin_amdgcn_s_setprio(1);
#pragma unroll
    for (int dg = 0; dg < 4; dg++) {
      bf16x8 v0 = *(const bf16x8*)&Vl[buf][dg * 16 + lr][8 * (g ^ (lr & 7))];
      bf16x8 v1 = *(const bf16x8*)&Vl[buf][dg * 16 + lr][8 * ((4 + g) ^ (lr & 7))];
      o_acc[dg] = __builtin_amdgcn_mfma_f32_16x16x32_bf16(pf[0], v0, o_acc[dg], 0, 0, 0);
      o_acc[dg] = __builtin_amdgcn_mfma_f32_16x16x32_bf16(pf[1], v1, o_acc[dg], 0, 0, 0);
    }
    __builtin_amdgcn_s_setprio(0);
    buf ^= 1;
  }
#undef STAGEKV

  {
    float l = lsum;
    l += __shfl_xor(l, 16);
    l += __shfl_xor(l, 32);
    float inv = 1.f / l;
    float invq[4];
#pragma unroll
    for (int r = 0; r < 4; r++) invq[r] = __shfl(inv, 4 * g + r);
#pragma unroll
    for (int dg = 0; dg < 4; dg++)
#pragma unroll
      for (int r = 0; r < 4; r++) {
        int qr = qbase + w * 16 + 4 * g + r;
        int col = h * 64 + dg * 16 + lr;
        Ob[((size_t)b * S_LEN + qr) * DM + col] = f2bf(o_acc[dg][r] * invq[r]);
      }
  }
}

// ---------------- wtrans (fallback path only)
__global__ __launch_bounds__(256) void wtrans(const float* __restrict__ Wq, const float* __restrict__ Wk,
                                              const float* __restrict__ Wv, const float* __restrict__ Wo,
                                              const int* __restrict__ mask,
                                              short* Tq, short* Tk, short* Tv, short* To, short* Mb) {
  const int z = blockIdx.z;
  const int tid = threadIdx.x;
  if (z == 4) {
    if (blockIdx.y == 0 && blockIdx.x < 16) {
      int i = blockIdx.x * 256 + tid;
      Mb[i] = mask[i] ? (short)0x3F80 : (short)0;
    }
    return;
  }
  const float* W = (z == 0) ? Wq : (z == 1) ? Wk : (z == 2) ? Wv : Wo;
  short* T = (z == 0) ? Tq : (z == 1) ? Tk : (z == 2) ? Tv : To;
  __shared__ short Tl[64][72];
  const int k0 = blockIdx.x * 64, n0 = blockIdx.y * 64;
  const int r = tid >> 2, c0 = (tid & 3) * 16;
#pragma unroll
  for (int j = 0; j < 4; j++) {
    float4 v = *(const float4*)&W[(size_t)(k0 + r) * DM + n0 + c0 + 4 * j];
    Tl[r][c0 + 4 * j + 0] = f2bf(v.x);
    Tl[r][c0 + 4 * j + 1] = f2bf(v.y);
    Tl[r][c0 + 4 * j + 2] = f2bf(v.z);
    Tl[r][c0 + 4 * j + 3] = f2bf(v.w);
  }
  __syncthreads();
  bf16x8 o0, o1;
#pragma unroll
  for (int j = 0; j < 8; j++) { o0[j] = Tl[c0 + j][r]; o1[j] = Tl[c0 + 8 + j][r]; }
  *(bf16x8*)&T[(size_t)(n0 + r) * DM + k0 + c0] = o0;
  *(bf16x8*)&T[(size_t)(n0 + r) * DM + k0 + c0 + 8] = o1;
}

extern "C" void kernel_launch(void* const* d_in, const int* in_sizes, int n_in,
                              void* d_out, int out_size, void* d_ws, size_t ws_size,
                              hipStream_t stream) {
  const float* query = (const float*)d_in[0];
  const float* key   = (const float*)d_in[1];
  const float* value = (const float*)d_in[2];
  const float* Wq = (const float*)d_in[3];
  const float* Wk = (const float*)d_in[4];
  const float* Wv = (const float*)d_in[5];
  const float* Wo = (const float*)d_in[6];
  const int* mask = (const int*)d_in[7];

  char* ws = (char*)d_ws;
  const size_t MB = 1 << 20;
  const bool big = ws_size >= 41 * MB;

  if (big) {
    // ws: xA = xq|xk|xv [0,24); Wt [24,30); WoT [30,32); Qb [32,40); Mb [40,+64KB)
    // d_out doubles as scratch: Kb [0,8MB), VbT [8,16MB) — consumed by attn11,
    // then overwritten by the final gemm5<1> write of d_out.
    short* xA  = (short*)(ws);
    short* xq  = xA;
    short* xk  = (short*)(ws + 8 * MB);
    short* xv  = (short*)(ws + 16 * MB);
    short* WqT = (short*)(ws + 24 * MB);   // Wt = WqT|WkT|WvT contiguous
    short* WkT = (short*)(ws + 26 * MB);
    short* WvT = (short*)(ws + 28 * MB);
    short* WoT = (short*)(ws + 30 * MB);
    short* Qb  = (short*)(ws + 32 * MB);
    short* Mb  = (short*)(ws + 40 * MB);
    short* Kb  = (short*)d_out;
    short* VbT = (short*)d_out + (size_t)4 * 1024 * 1024;  // +8 MB
    short* Ob  = xv;  // xv consumed by gemm5<0> before attn11 writes Ob

    dim3 pg(1024, 4);
    prep<<<pg, 256, 0, stream>>>(query, key, value, Wq, Wk, Wv, Wo, mask,
                                 xq, xk, xv, WqT, WkT, WvT, WoT, Mb);

    dim3 g5(8, 96);  // 768 blocks
    gemm5<0><<<g5, 256, 0, stream>>>(xA, WqT, mask, Qb, Kb, VbT, nullptr);

    dim3 ag(S_LEN / 64, 2 * NHEAD);  // 1024 blocks
    attn11<<<ag, 256, 0, stream>>>(Qb, Kb, VbT, Mb, Ob);

    dim3 g6(8, 32);  // 256 blocks
    gemm5<1><<<g6, 256, 0, stream>>>(Ob, WoT, mask, nullptr, nullptr, nullptr, (float*)d_out);
  } else {
    short* Qb  = (short*)(ws);
    short* Kb  = (short*)(ws + 8 * MB);
    short* VbT = (short*)(ws + 16 * MB);
    short* WqT = (short*)(ws + 24 * MB);
    short* WkT = (short*)(ws + 26 * MB);
    short* WvT = (short*)(ws + 28 * MB);
    short* Ob  = (short*)(ws + 24 * MB);

    dim3 tgrid(16, 16, 3);
    wtrans<<<tgrid, 256, 0, stream>>>(Wq, Wk, Wv, Wo, mask, WqT, WkT, WvT, WqT, WqT);

    dim3 gq(DM / 64, (2 * S_LEN) / 128);
    gemm2<0, 1, 3><<<gq, 256, 0, stream>>>(query, WqT, Qb, 2 * S_LEN, DM, DM);
    gemm2<0, 1, 1><<<gq, 256, 0, stream>>>(key,   WkT, Kb, 2 * S_LEN, DM, DM);
    dim3 gv((2 * S_LEN) / 64, DM / 128);
    gemm2<1, 0, 2><<<gv, 256, 0, stream>>>(WvT, value, VbT, DM, 2 * S_LEN, DM);

    dim3 ag(S_LEN / 64, 2 * NHEAD);
    attn7<<<ag, 256, 0, stream>>>(Qb, Kb, VbT, mask, Ob);

    gemm2<1, 2, 0><<<gq, 256, 0, stream>>>(Ob, Wo, (float*)d_out, 2 * S_LEN, DM, DM);
  }
}